// Round 14
// baseline (443.557 us; speedup 1.0000x reference)
//
#include <hip/hip_runtime.h>

#define BB 4
#define SS 2048
#define EE 512
#define HH 8
#define DKK 64
#define MM (BB*SS)

typedef unsigned short u16;
typedef unsigned int u32;
typedef unsigned long long u64;
typedef __attribute__((ext_vector_type(8))) short short8;
typedef __attribute__((ext_vector_type(4))) short short4v;
typedef __attribute__((ext_vector_type(4))) float f32x4;

__device__ inline u16 f2bf(float f) {            // RNE f32 -> bf16
  union { float f; u32 u; } v; v.f = f;
  u32 r = v.u + 0x7fff + ((v.u >> 16) & 1);
  return (u16)(r >> 16);
}
__device__ inline float bf2f(u16 u) {
  union { u32 u; float f; } v; v.u = ((u32)u) << 16;
  return v.f;
}
__device__ inline void split2(float f, u16 &h, u16 &l) {
  h = f2bf(f);
  l = f2bf(f - bf2f(h));
}

// DPP row-rotate (within 16-lane rows), VALU-speed cross-lane for reductions.
template<int CTRL>
__device__ inline float fdpp(float x) {
  return __builtin_bit_cast(float,
      __builtin_amdgcn_update_dpp(0, __builtin_bit_cast(int, x), CTRL, 0xf, 0xf, true));
}
__device__ inline float rmax16(float x) {
  x = fmaxf(x, fdpp<0x121>(x));
  x = fmaxf(x, fdpp<0x122>(x));
  x = fmaxf(x, fdpp<0x124>(x));
  x = fmaxf(x, fdpp<0x128>(x));
  return x;
}
__device__ inline float rsum16(float x) {
  x += fdpp<0x121>(x);
  x += fdpp<0x122>(x);
  x += fdpp<0x124>(x);
  x += fdpp<0x128>(x);
  return x;
}

// ---------- mask [B,S,S] int32 -> bitmask [B*S][32] u64 ----------
__global__ __launch_bounds__(256) void maskpack(const int* __restrict__ mask,
                                                u64* __restrict__ mb) {
  const int bq = blockIdx.x;
  const int w = threadIdx.x >> 6, l = threadIdx.x & 63;
  const int* src = mask + (size_t)bq * SS;
  #pragma unroll
  for (int it = 0; it < 8; ++it) {
    int tb = it * 4 + w;
    int m = src[tb * 64 + l];
    u64 bits = __ballot(m != 0);
    if (l == 0) mb[(size_t)bq * 32 + tb] = bits;
  }
}

// ---------- one-pass f32 -> bf16 hi(/lo) split, grid-stride, f32x4 vectorized ----------
template<int HAS_LO>
__global__ __launch_bounds__(256) void presplit(const float* __restrict__ in,
                                                u16* __restrict__ hi,
                                                u16* __restrict__ lo, int n4) {
  int idx = blockIdx.x * 256 + threadIdx.x;
  const int stride = gridDim.x * 256;
  for (; idx < n4; idx += stride) {
    f32x4 v = *((const f32x4*)in + idx);
    u16 h[4], l[4];
    #pragma unroll
    for (int j = 0; j < 4; ++j) split2(v[j], h[j], l[j]);
    *((short4v*)hi + idx) = (short4v){(short)h[0], (short)h[1], (short)h[2], (short)h[3]};
    if (HAS_LO)
      *((short4v*)lo + idx) = (short4v){(short)l[0], (short)l[1], (short)l[2], (short)l[3]};
  }
}

// ---------- Projection GEMM on pre-split bf16 inputs: pure-copy staging ----------
// C[m,n] = (sum_k A[m,k]*W[n,k] + bias[n]) * cscale.  COMP=1: 3-term compensated.
template<int COMP>
__global__ __launch_bounds__(256) void proj(
    const u16* __restrict__ Ag, const u16* __restrict__ Alg,
    const u16* __restrict__ Wg, const u16* __restrict__ Wlg,
    const float* __restrict__ bias, u16* __restrict__ Chi, u16* __restrict__ Clo,
    float cscale)
{
  __shared__ __align__(16) u16 Ah[128][72];
  __shared__ __align__(16) u16 Al[COMP ? 128 : 1][72];
  __shared__ __align__(16) u16 Bh[64][72];
  __shared__ __align__(16) u16 Bl[COMP ? 64 : 1][72];
  const int m0 = blockIdx.x * 128, n0 = blockIdx.y * 64;
  const int tid = threadIdx.x, w = tid >> 6, l = tid & 63;
  const int row = l & 15, kq = (l >> 4) * 8;
  f32x4 acc[2][4];
  #pragma unroll
  for (int i = 0; i < 2; ++i)
    #pragma unroll
    for (int j = 0; j < 4; ++j) acc[i][j] = (f32x4){0.f, 0.f, 0.f, 0.f};

  for (int k0 = 0; k0 < 512; k0 += 64) {
    __syncthreads();
    #pragma unroll
    for (int i = 0; i < 4; ++i) {            // A tile 128x64 bf16 (hi/lo)
      int u = tid + i * 256; int r = u >> 3, c = (u & 7) * 8;
      *(short8*)&Ah[r][c] = *(const short8*)&Ag[(size_t)(m0 + r) * 512 + k0 + c];
      if (COMP)
        *(short8*)&Al[r][c] = *(const short8*)&Alg[(size_t)(m0 + r) * 512 + k0 + c];
    }
    #pragma unroll
    for (int i = 0; i < 2; ++i) {            // W tile 64x64 bf16 (hi/lo)
      int u = tid + i * 256; int r = u >> 3, c = (u & 7) * 8;
      *(short8*)&Bh[r][c] = *(const short8*)&Wg[(size_t)(n0 + r) * 512 + k0 + c];
      if (COMP)
        *(short8*)&Bl[r][c] = *(const short8*)&Wlg[(size_t)(n0 + r) * 512 + k0 + c];
    }
    __syncthreads();
    short8 ah[2][2], al[2][2], bh[4][2], bl[4][2];
    #pragma unroll
    for (int mf = 0; mf < 2; ++mf)
      #pragma unroll
      for (int ks = 0; ks < 2; ++ks) {
        ah[mf][ks] = *(const short8*)&Ah[w * 32 + mf * 16 + row][ks * 32 + kq];
        if (COMP) al[mf][ks] = *(const short8*)&Al[w * 32 + mf * 16 + row][ks * 32 + kq];
      }
    #pragma unroll
    for (int nf = 0; nf < 4; ++nf)
      #pragma unroll
      for (int ks = 0; ks < 2; ++ks) {
        bh[nf][ks] = *(const short8*)&Bh[nf * 16 + row][ks * 32 + kq];
        if (COMP) bl[nf][ks] = *(const short8*)&Bl[nf * 16 + row][ks * 32 + kq];
      }
    #pragma unroll
    for (int mf = 0; mf < 2; ++mf)
      #pragma unroll
      for (int nf = 0; nf < 4; ++nf)
        #pragma unroll
        for (int ks = 0; ks < 2; ++ks) {
          acc[mf][nf] = __builtin_amdgcn_mfma_f32_16x16x32_bf16(
              ah[mf][ks], bh[nf][ks], acc[mf][nf], 0, 0, 0);
          if (COMP) {
            acc[mf][nf] = __builtin_amdgcn_mfma_f32_16x16x32_bf16(
                ah[mf][ks], bl[nf][ks], acc[mf][nf], 0, 0, 0);
            acc[mf][nf] = __builtin_amdgcn_mfma_f32_16x16x32_bf16(
                al[mf][ks], bh[nf][ks], acc[mf][nf], 0, 0, 0);
          }
        }
  }
  #pragma unroll
  for (int mf = 0; mf < 2; ++mf)
    #pragma unroll
    for (int nf = 0; nf < 4; ++nf)
      #pragma unroll
      for (int r = 0; r < 4; ++r) {
        int m = m0 + w * 32 + mf * 16 + ((l >> 4) << 2) + r;
        int n = n0 + nf * 16 + (l & 15);
        float c = (acc[mf][nf][r] + bias[n]) * cscale;
        size_t idx = (size_t)m * 512 + n;
        if (COMP) { u16 h, lo; split2(c, h, lo); Chi[idx] = h; Clo[idx] = lo; }
        else Chi[idx] = f2bf(c);
      }
}

// ---------- Output GEMM: X bf16 x Woh bf16 -> f32 out ----------
__global__ __launch_bounds__(256) void gemm_out(
    const u16* __restrict__ A, const u16* __restrict__ Wg,
    const float* __restrict__ bias, float* __restrict__ C)
{
  __shared__ __align__(16) u16 As[128][72];
  __shared__ __align__(16) u16 Bs[64][72];
  const int m0 = blockIdx.x * 128, n0 = blockIdx.y * 64;
  const int tid = threadIdx.x, w = tid >> 6, l = tid & 63;
  const int row = l & 15, kq = (l >> 4) * 8;
  f32x4 acc[2][4];
  #pragma unroll
  for (int i = 0; i < 2; ++i)
    #pragma unroll
    for (int j = 0; j < 4; ++j) acc[i][j] = (f32x4){0.f, 0.f, 0.f, 0.f};

  for (int k0 = 0; k0 < 512; k0 += 64) {
    __syncthreads();
    #pragma unroll
    for (int i = 0; i < 4; ++i) {
      int u = tid + i * 256; int r = u >> 3, c = (u & 7) * 8;
      *(short8*)&As[r][c] = *(const short8*)&A[(size_t)(m0 + r) * 512 + k0 + c];
    }
    #pragma unroll
    for (int i = 0; i < 2; ++i) {
      int u = tid + i * 256; int r = u >> 3, c = (u & 7) * 8;
      *(short8*)&Bs[r][c] = *(const short8*)&Wg[(size_t)(n0 + r) * 512 + k0 + c];
    }
    __syncthreads();
    short8 a[2][2], bfr[4][2];
    #pragma unroll
    for (int mf = 0; mf < 2; ++mf)
      #pragma unroll
      for (int ks = 0; ks < 2; ++ks)
        a[mf][ks] = *(const short8*)&As[w * 32 + mf * 16 + row][ks * 32 + kq];
    #pragma unroll
    for (int nf = 0; nf < 4; ++nf)
      #pragma unroll
      for (int ks = 0; ks < 2; ++ks)
        bfr[nf][ks] = *(const short8*)&Bs[nf * 16 + row][ks * 32 + kq];
    #pragma unroll
    for (int mf = 0; mf < 2; ++mf)
      #pragma unroll
      for (int nf = 0; nf < 4; ++nf)
        #pragma unroll
        for (int ks = 0; ks < 2; ++ks)
          acc[mf][nf] = __builtin_amdgcn_mfma_f32_16x16x32_bf16(
              a[mf][ks], bfr[nf][ks], acc[mf][nf], 0, 0, 0);
  }
  #pragma unroll
  for (int mf = 0; mf < 2; ++mf)
    #pragma unroll
    for (int nf = 0; nf < 4; ++nf)
      #pragma unroll
      for (int r = 0; r < 4; ++r) {
        int m = m0 + w * 32 + mf * 16 + ((l >> 4) << 2) + r;
        int n = n0 + nf * 16 + (l & 15);
        C[(size_t)m * 512 + n] = acc[mf][nf][r] + bias[n];
      }
}

// ---------- Flash attention (unchanged from round 13's measured kernel) ----------
__global__ __launch_bounds__(256) void attn(
    const u16* __restrict__ Qhi, const u16* __restrict__ Qlo,
    const u16* __restrict__ Khi, const u16* __restrict__ Klo,
    const u16* __restrict__ V, const u64* __restrict__ MB,
    u16* __restrict__ X)
{
  __shared__ __align__(16) u16 KhiS[64][64];
  __shared__ __align__(16) u16 KloS[64][64];
  __shared__ __align__(16) u16 VtS[64][64];
  __shared__ __align__(16) u16 Pl[64][64];
  const int b = blockIdx.z, h = blockIdx.y, q0 = blockIdx.x * 64;
  const int tid = threadIdx.x, w = tid >> 6, l = tid & 63;
  const int row = l & 15, kq = (l >> 4) * 8;
  const int r0 = tid >> 3;
  const int c0 = (tid & 7) * 8;

  const size_t qbase = ((size_t)(b * SS) + q0 + w * 16 + row) * EE + h * DKK;
  short8 qh[2], ql[2];
  #pragma unroll
  for (int ks = 0; ks < 2; ++ks) {
    qh[ks] = *(const short8*)&Qhi[qbase + ks * 32 + kq];
    ql[ks] = *(const short8*)&Qlo[qbase + ks * 32 + kq];
  }

  float mrow[4], lrow[4];
  f32x4 acco[4];
  #pragma unroll
  for (int r = 0; r < 4; ++r) { mrow[r] = -INFINITY; lrow[r] = 0.f; }
  #pragma unroll
  for (int f = 0; f < 4; ++f) acco[f] = (f32x4){0.f, 0.f, 0.f, 0.f};

  const int qr0 = q0 + w * 16 + ((l >> 4) << 2);
  const size_t mbase = ((size_t)(b * SS) + qr0) * 32;

  short8 sh[2], sl[2], sv[2];
  u64 wb[4], wbn[4];

  #pragma unroll
  for (int i = 0; i < 2; ++i) {
    size_t g = ((size_t)(b * SS) + r0 + 32 * i) * EE + h * DKK + c0;
    sh[i] = *(const short8*)&Khi[g];
    sl[i] = *(const short8*)&Klo[g];
    sv[i] = *(const short8*)&V[g];
  }
  #pragma unroll
  for (int r = 0; r < 4; ++r) wb[r] = MB[mbase + r * 32] >> (l & 15);
  #pragma unroll
  for (int i = 0; i < 2; ++i) {
    int rr = r0 + 32 * i;
    int kc = c0 ^ ((rr & 7) << 3);
    *(short8*)&KhiS[rr][kc] = sh[i];
    *(short8*)&KloS[rr][kc] = sl[i];
    #pragma unroll
    for (int j = 0; j < 8; ++j) {
      int d = c0 + j;
      VtS[d][rr ^ (((d & 7) ^ (d >> 3)) << 3)] = (u16)sv[i][j];
    }
  }
  __syncthreads();

  for (int t0 = 0; t0 < SS; t0 += 64) {
    const bool more = (t0 + 64 < SS);
    if (more) {
      #pragma unroll
      for (int i = 0; i < 2; ++i) {
        size_t g = ((size_t)(b * SS) + t0 + 64 + r0 + 32 * i) * EE + h * DKK + c0;
        sh[i] = *(const short8*)&Khi[g];
        sl[i] = *(const short8*)&Klo[g];
        sv[i] = *(const short8*)&V[g];
      }
      #pragma unroll
      for (int r = 0; r < 4; ++r)
        wbn[r] = MB[mbase + r * 32 + ((t0 >> 6) + 1)] >> (l & 15);
    }

    f32x4 sacc[4];
    #pragma unroll
    for (int f = 0; f < 4; ++f) sacc[f] = (f32x4){0.f, 0.f, 0.f, 0.f};
    #pragma unroll
    for (int f = 0; f < 4; ++f) {
      int krow = f * 16 + row;
      int ksw = (krow & 7) << 3;
      #pragma unroll
      for (int ks = 0; ks < 2; ++ks) {
        short8 kh = *(const short8*)&KhiS[krow][(ks * 32 + kq) ^ ksw];
        short8 kl = *(const short8*)&KloS[krow][(ks * 32 + kq) ^ ksw];
        sacc[f] = __builtin_amdgcn_mfma_f32_16x16x32_bf16(qh[ks], kh, sacc[f], 0, 0, 0);
        sacc[f] = __builtin_amdgcn_mfma_f32_16x16x32_bf16(qh[ks], kl, sacc[f], 0, 0, 0);
        sacc[f] = __builtin_amdgcn_mfma_f32_16x16x32_bf16(ql[ks], kh, sacc[f], 0, 0, 0);
      }
    }

    float sval[4][4];
    #pragma unroll
    for (int f = 0; f < 4; ++f)
      #pragma unroll
      for (int r = 0; r < 4; ++r)
        sval[f][r] = ((wb[r] >> (16 * f)) & 1ULL) ? sacc[f][r] : -1e9f;

    #pragma unroll
    for (int r = 0; r < 4; ++r) {
      float mx = fmaxf(fmaxf(sval[0][r], sval[1][r]), fmaxf(sval[2][r], sval[3][r]));
      mx = rmax16(mx);
      float mnew = fmaxf(mrow[r], mx);
      float alpha = __expf(mrow[r] - mnew);
      float rs = 0.f;
      #pragma unroll
      for (int f = 0; f < 4; ++f) {
        float p = __expf(sval[f][r] - mnew);
        sval[f][r] = p; rs += p;
      }
      rs = rsum16(rs);
      lrow[r] = lrow[r] * alpha + rs;
      mrow[r] = mnew;
      #pragma unroll
      for (int f = 0; f < 4; ++f) acco[f][r] *= alpha;
    }

    #pragma unroll
    for (int f = 0; f < 4; ++f)
      #pragma unroll
      for (int r = 0; r < 4; ++r) {
        int rr = ((l >> 4) << 2) + r;
        Pl[w * 16 + rr][(f * 16 + (l & 15)) ^ (((rr & 7) ^ (rr >> 3)) << 3)] = f2bf(sval[f][r]);
      }

    {
      int psw = ((row & 7) ^ (row >> 3)) << 3;
      #pragma unroll
      for (int f2 = 0; f2 < 4; ++f2) {
        int d = f2 * 16 + row;
        int vsw = ((d & 7) ^ (d >> 3)) << 3;
        #pragma unroll
        for (int ks = 0; ks < 2; ++ks) {
          short8 p = *(const short8*)&Pl[w * 16 + row][(ks * 32 + kq) ^ psw];
          short8 vvf = *(const short8*)&VtS[d][(ks * 32 + kq) ^ vsw];
          acco[f2] = __builtin_amdgcn_mfma_f32_16x16x32_bf16(p, vvf, acco[f2], 0, 0, 0);
        }
      }
    }

    __syncthreads();
    if (more) {
      #pragma unroll
      for (int i = 0; i < 2; ++i) {
        int rr = r0 + 32 * i;
        int kc = c0 ^ ((rr & 7) << 3);
        *(short8*)&KhiS[rr][kc] = sh[i];
        *(short8*)&KloS[rr][kc] = sl[i];
        #pragma unroll
        for (int j = 0; j < 8; ++j) {
          int d = c0 + j;
          VtS[d][rr ^ (((d & 7) ^ (d >> 3)) << 3)] = (u16)sv[i][j];
        }
      }
      #pragma unroll
      for (int r = 0; r < 4; ++r) wb[r] = wbn[r];
    }
    __syncthreads();
  }

  // X[b][h*256 + q>>3][(q&7)*64 + d]  (reference reshape quirk)
  #pragma unroll
  for (int f2 = 0; f2 < 4; ++f2)
    #pragma unroll
    for (int r = 0; r < 4; ++r) {
      int q = q0 + w * 16 + ((l >> 4) << 2) + r;
      int d = f2 * 16 + (l & 15);
      float o = acco[f2][r] / lrow[r];
      int sp = h * 256 + (q >> 3);
      int ep = ((q & 7) << 6) + d;
      X[((size_t)(b * SS) + sp) * EE + ep] = f2bf(o);
    }
}

extern "C" void kernel_launch(void* const* d_in, const int* in_sizes, int n_in,
                              void* d_out, int out_size, void* d_ws, size_t ws_size,
                              hipStream_t stream) {
  const float* query  = (const float*)d_in[0];
  const float* key_in = (const float*)d_in[1];
  const float* value  = (const float*)d_in[2];
  const int*   mask   = (const int*)d_in[3];
  const float* Wq = (const float*)d_in[4];
  const float* bq = (const float*)d_in[5];
  const float* Wk = (const float*)d_in[6];
  const float* bk = (const float*)d_in[7];
  const float* Wv = (const float*)d_in[8];
  const float* bv = (const float*)d_in[9];
  const float* Wo = (const float*)d_in[10];
  const float* bo = (const float*)d_in[11];

  u16* ws = (u16*)d_ws;
  const size_t NE = (size_t)MM * EE;   // 4.19M elems
  const size_t WN = (size_t)EE * EE;   // 262k elems
  u16* Qhi = ws;
  u16* Qlo = ws + NE;
  u16* Khi = ws + 2 * NE;
  u16* Klo = ws + 3 * NE;
  u16* Vp  = ws + 4 * NE;
  u16* Sh  = ws + 5 * NE;              // presplit scratch hi (query/key/value, serial reuse)
  u16* Sl  = ws + 6 * NE;              // presplit scratch lo; dead after proj K
  u16* X   = Sl;                       // X aliases Sl (attn runs after proj K/V)
  u16* Wqh = ws + 7 * NE;
  u16* Wql = Wqh + WN;
  u16* Wkh = Wqh + 2 * WN;
  u16* Wkl = Wqh + 3 * WN;
  u16* Wvh = Wqh + 4 * WN;
  u16* Woh = Wqh + 5 * WN;
  u64* MBb = (u64*)(ws + 7 * NE + 6 * WN);  // 2 MB bitmask

  const int n4NE = (int)(NE / 4);
  const int n4WN = (int)(WN / 4);

  dim3 gblk(MM / 128, EE / 64);
  maskpack<<<MM, 256, 0, stream>>>(mask, MBb);
  presplit<1><<<256, 256, 0, stream>>>(Wq, Wqh, Wql, n4WN);
  presplit<1><<<256, 256, 0, stream>>>(Wk, Wkh, Wkl, n4WN);
  presplit<0><<<256, 256, 0, stream>>>(Wv, Wvh, nullptr, n4WN);
  presplit<0><<<256, 256, 0, stream>>>(Wo, Woh, nullptr, n4WN);

  presplit<1><<<2048, 256, 0, stream>>>(query, Sh, Sl, n4NE);
  proj<1><<<gblk, 256, 0, stream>>>(Sh, Sl, Wqh, Wql, bq, Qhi, Qlo, 8.0f);
  presplit<1><<<2048, 256, 0, stream>>>(key_in, Sh, Sl, n4NE);
  proj<1><<<gblk, 256, 0, stream>>>(Sh, Sl, Wkh, Wkl, bk, Khi, Klo, 1.0f);
  presplit<0><<<2048, 256, 0, stream>>>(value, Sh, nullptr, n4NE);
  proj<0><<<gblk, 256, 0, stream>>>(Sh, nullptr, Wvh, nullptr, bv, Vp, nullptr, 1.0f);

  attn<<<dim3(SS / 64, HH, BB), 256, 0, stream>>>(Qhi, Qlo, Khi, Klo, Vp, MBb, X);
  gemm_out<<<gblk, 256, 0, stream>>>(X, Woh, bo, (float*)d_out);
}